// Round 1
// baseline (389.096 us; speedup 1.0000x reference)
//
#include <hip/hip_runtime.h>
#include <math.h>

#define BB   2
#define LL   2048
#define HIDD 2048
#define NHH  16
#define HDD  128
#define QKVN 6144   // 3*HIDD

typedef unsigned short u16;
typedef float  f32x4 __attribute__((ext_vector_type(4)));
typedef __bf16 bf16x8 __attribute__((ext_vector_type(8)));

static __device__ __forceinline__ u16 f2bf(float x){
  unsigned u = __float_as_uint(x);
  return (u16)((u + 0x7fffu + ((u >> 16) & 1u)) >> 16);
}
static __device__ __forceinline__ float bf2f(u16 b){
  return __uint_as_float(((unsigned)b) << 16);
}
static __device__ __forceinline__ void gl_lds16(const void* g, void* l){
  __builtin_amdgcn_global_load_lds(
      (__attribute__((address_space(1))) void*)(void*)g,
      (__attribute__((address_space(3))) void*)l,
      16, 0, 0);
}

// ---------------- prep kernels ----------------

__global__ void cvt_f32_bf16_k(const float* __restrict__ src, u16* __restrict__ dst, int n4){
  int i = blockIdx.x * blockDim.x + threadIdx.x;
  if (i >= n4) return;
  float4 v = ((const float4*)src)[i];
  ushort4 o;
  o.x = f2bf(v.x); o.y = f2bf(v.y); o.z = f2bf(v.z); o.w = f2bf(v.w);
  ((ushort4*)dst)[i] = o;
}

// src: R x C f32 (row-major) -> dst: C x R bf16
__global__ void transpose_cvt_k(const float* __restrict__ src, u16* __restrict__ dst, int R, int C){
  __shared__ float t[32][33];
  int c0 = blockIdx.x * 32, r0 = blockIdx.y * 32;
  int tx = threadIdx.x, ty = threadIdx.y;
  #pragma unroll
  for (int i = 0; i < 32; i += 8) t[ty + i][tx] = src[(size_t)(r0 + ty + i) * C + c0 + tx];
  __syncthreads();
  #pragma unroll
  for (int i = 0; i < 32; i += 8) dst[(size_t)(c0 + ty + i) * R + r0 + tx] = f2bf(t[tx][ty + i]);
}

// in-place RoPE on q,k sections of qkv (bf16). idx over B*L*NH*64
__global__ void rope_k(u16* __restrict__ qkv){
  int idx = blockIdx.x * blockDim.x + threadIdx.x;
  int d   = idx & 63;
  int h   = (idx >> 6) & 15;
  int row = idx >> 10;           // b*L + l
  int l   = row & (LL - 1);
  float fr = __expf(-(float)d * 0.17988946f);   // ln(1e5)/64
  float th = (float)l * 0.25f * fr;             // pos/ROPE_SCALE * freq
  float s, c;
  sincosf(th, &s, &c);
  size_t base = (size_t)row * QKVN + h * HDD + d;
  #pragma unroll
  for (int part = 0; part < 2; part++){         // q then k
    float x1 = bf2f(qkv[base]), x2 = bf2f(qkv[base + 64]);
    qkv[base]      = f2bf(x1 * c - x2 * s);
    qkv[base + 64] = f2bf(x1 * s + x2 * c);
    base += HIDD;
  }
}

// v section of qkv -> vt[(b,h), d, l]
__global__ void build_vt_k(const u16* __restrict__ qkv, u16* __restrict__ vt){
  __shared__ u16 t[32][33];
  int bh = blockIdx.z;
  int b = bh >> 4, h = bh & 15;
  const u16* src = qkv + (size_t)b * LL * QKVN + 2 * HIDD + h * HDD; // [l][d] stride QKVN
  u16* dst = vt + (size_t)bh * HDD * LL;                              // [d][l] stride LL
  int d0 = blockIdx.x * 32, l0 = blockIdx.y * 32;
  int tx = threadIdx.x, ty = threadIdx.y;
  #pragma unroll
  for (int i = 0; i < 32; i += 8) t[ty + i][tx] = src[(size_t)(l0 + ty + i) * QKVN + d0 + tx];
  __syncthreads();
  #pragma unroll
  for (int i = 0; i < 32; i += 8) dst[(size_t)(d0 + ty + i) * LL + l0 + tx] = t[tx][ty + i];
}

// ---------------- GEMM: C[M,N] = A[M,K] * Bt[N,K]^T  (bf16 in, f32 acc) ----------------

template<int OUT_BF16>
__global__ __launch_bounds__(256) void gemm_bt_k(
    const u16* __restrict__ A, const u16* __restrict__ Bt,
    void* __restrict__ Cout, int M, int N, int K)
{
  __shared__ __align__(16) u16 As[128 * 64];
  __shared__ __align__(16) u16 Bs[128 * 64];
  const int tid = threadIdx.x, lane = tid & 63, wv = tid >> 6;
  const int wr = wv >> 1, wc = wv & 1;
  const int m0 = blockIdx.y * 128, n0 = blockIdx.x * 128;
  const int rq = lane >> 4, cl = lane & 15;

  const f32x4 Z = {0.f, 0.f, 0.f, 0.f};
  f32x4 acc[4][4];
  #pragma unroll
  for (int m = 0; m < 4; m++)
    #pragma unroll
    for (int n = 0; n < 4; n++) acc[m][n] = Z;

  for (int kt = 0; kt < K; kt += 64){
    // stage: linear LDS dest, inverse-swizzled global source
    #pragma unroll
    for (int i = 0; i < 4; i++){
      int fb = (i * 4 + wv) * 64;          // wave-uniform 16B-chunk base
      int p  = (fb + lane) * 16;           // this lane's physical LDS byte
      int r  = p >> 7;                     // tile row (128B rows)
      int cbs = (p & 127) ^ ((r & 7) << 4);
      gl_lds16(A  + (size_t)(m0 + r) * K + kt + (cbs >> 1), &As[fb * 8]);
      gl_lds16(Bt + (size_t)(n0 + r) * K + kt + (cbs >> 1), &Bs[fb * 8]);
    }
    __syncthreads();
    #pragma unroll
    for (int ks = 0; ks < 2; ks++){
      const int kb = ks * 64 + rq * 16;    // k byte offset in row
      bf16x8 a[4], b[4];
      #pragma unroll
      for (int m = 0; m < 4; m++){
        int r = wr * 64 + m * 16 + cl;
        a[m] = *(const bf16x8*)((const char*)As + r * 128 + (kb ^ ((r & 7) << 4)));
      }
      #pragma unroll
      for (int n = 0; n < 4; n++){
        int r = wc * 64 + n * 16 + cl;
        b[n] = *(const bf16x8*)((const char*)Bs + r * 128 + (kb ^ ((r & 7) << 4)));
      }
      #pragma unroll
      for (int m = 0; m < 4; m++)
        #pragma unroll
        for (int n = 0; n < 4; n++)
          acc[m][n] = __builtin_amdgcn_mfma_f32_16x16x32_bf16(a[m], b[n], acc[m][n], 0, 0, 0);
    }
    __syncthreads();
  }

  #pragma unroll
  for (int m = 0; m < 4; m++){
    int gr0 = m0 + wr * 64 + m * 16 + rq * 4;
    #pragma unroll
    for (int n = 0; n < 4; n++){
      int gc = n0 + wc * 64 + n * 16 + cl;
      #pragma unroll
      for (int rr = 0; rr < 4; rr++){
        if (OUT_BF16) ((u16*)Cout)[(size_t)(gr0 + rr) * N + gc] = f2bf(acc[m][n][rr]);
        else          ((float*)Cout)[(size_t)(gr0 + rr) * N + gc] = acc[m][n][rr];
      }
    }
  }
}

// ---------------- flash attention ----------------
// grid: (L/64, B*NH); block 256 (4 waves x 16 q-rows)

__global__ __launch_bounds__(256) void attn_k(
    const u16* __restrict__ qkv, const u16* __restrict__ vt,
    u16* __restrict__ aout)
{
  __shared__ __align__(16) u16 Ks[64 * 128];
  __shared__ __align__(16) u16 Vs[128 * 64];
  __shared__ __align__(16) u16 Ps[4 * 16 * 64];
  const int tid = threadIdx.x, lane = tid & 63, wv = tid >> 6;
  const int qi = blockIdx.x, bh = blockIdx.y;
  const int b = bh >> 4, h = bh & 15;
  const int rq = lane >> 4, cl = lane & 15;
  const float scale = 0.08838834764831845f;  // 1/sqrt(128)

  // Q fragments hoisted to registers: wave's 16 q-rows
  bf16x8 qf[4];
  {
    const u16* qbase = qkv + (size_t)(b * LL + qi * 64 + wv * 16 + cl) * QKVN + h * HDD + rq * 8;
    #pragma unroll
    for (int ks = 0; ks < 4; ks++) qf[ks] = *(const bf16x8*)(qbase + ks * 32);
  }

  const f32x4 Z = {0.f, 0.f, 0.f, 0.f};
  f32x4 acco[8];
  #pragma unroll
  for (int n = 0; n < 8; n++) acco[n] = Z;
  float mst[4], lst[4];
  #pragma unroll
  for (int rr = 0; rr < 4; rr++){ mst[rr] = -INFINITY; lst[rr] = 0.f; }

  char* pbase = (char*)Ps + wv * 2048;

  for (int j = 0; j <= qi; j++){
    const int kv0 = j * 64;
    #pragma unroll
    for (int i = 0; i < 4; i++){
      int fb = (i * 4 + wv) * 64;
      int p  = (fb + lane) * 16;
      { int r = p >> 8; int cbs = (p & 255) ^ ((r & 7) << 4);   // Ks: [64][128] bf16
        gl_lds16(qkv + (size_t)(b * LL + kv0 + r) * QKVN + HIDD + h * HDD + (cbs >> 1), &Ks[fb * 8]); }
      { int r = p >> 7; int cbs = (p & 127) ^ ((r & 7) << 4);   // Vs: [128][64] bf16 (V^T)
        gl_lds16(vt + (size_t)(bh * HDD + r) * LL + kv0 + (cbs >> 1), &Vs[fb * 8]); }
    }
    __syncthreads();

    // S = Q K^T (16 x 64 per wave)
    f32x4 s[4];
    #pragma unroll
    for (int ct = 0; ct < 4; ct++) s[ct] = Z;
    #pragma unroll
    for (int ks = 0; ks < 4; ks++){
      const int kb = ks * 64 + rq * 16;
      #pragma unroll
      for (int ct = 0; ct < 4; ct++){
        int r = ct * 16 + cl;
        bf16x8 bfr = *(const bf16x8*)((const char*)Ks + r * 256 + (kb ^ ((r & 7) << 4)));
        s[ct] = __builtin_amdgcn_mfma_f32_16x16x32_bf16(qf[ks], bfr, s[ct], 0, 0, 0);
      }
    }

    // scale + causal mask + online softmax
    float p4[4][4], mx[4];
    #pragma unroll
    for (int rr = 0; rr < 4; rr++) mx[rr] = -1e30f;
    const int qg = qi * 64 + wv * 16 + rq * 4;  // global q row base for this lane
    #pragma unroll
    for (int ct = 0; ct < 4; ct++){
      int col = kv0 + ct * 16 + cl;
      #pragma unroll
      for (int rr = 0; rr < 4; rr++){
        float v = s[ct][rr] * scale;
        if (col > qg + rr) v = -1e30f;  // only triggers on the diagonal tile
        p4[ct][rr] = v;
        mx[rr] = fmaxf(mx[rr], v);
      }
    }
    #pragma unroll
    for (int off = 1; off < 16; off <<= 1)
      #pragma unroll
      for (int rr = 0; rr < 4; rr++)
        mx[rr] = fmaxf(mx[rr], __shfl_xor(mx[rr], off, 64));

    float fsc[4], rs[4];
    #pragma unroll
    for (int rr = 0; rr < 4; rr++){
      float mn = fmaxf(mst[rr], mx[rr]);
      fsc[rr] = __expf(mst[rr] - mn);
      mst[rr] = mn;
      rs[rr] = 0.f;
    }
    #pragma unroll
    for (int ct = 0; ct < 4; ct++)
      #pragma unroll
      for (int rr = 0; rr < 4; rr++){
        float e = __expf(p4[ct][rr] - mst[rr]);
        p4[ct][rr] = e;
        rs[rr] += e;
      }
    #pragma unroll
    for (int off = 1; off < 16; off <<= 1)
      #pragma unroll
      for (int rr = 0; rr < 4; rr++)
        rs[rr] += __shfl_xor(rs[rr], off, 64);
    #pragma unroll
    for (int rr = 0; rr < 4; rr++) lst[rr] = lst[rr] * fsc[rr] + rs[rr];
    #pragma unroll
    for (int n = 0; n < 8; n++)
      #pragma unroll
      for (int rr = 0; rr < 4; rr++) acco[n][rr] *= fsc[rr];

    // P -> per-wave LDS (swizzled), C-layout -> A-layout round trip
    #pragma unroll
    for (int ct = 0; ct < 4; ct++)
      #pragma unroll
      for (int rr = 0; rr < 4; rr++){
        int row = rq * 4 + rr;
        int colb = (ct * 16 + cl) * 2;
        *(u16*)(pbase + row * 128 + (colb ^ ((row & 7) << 4))) = f2bf(p4[ct][rr]);
      }

    // O += P V  (in-wave DS ordering makes the read-after-write safe)
    #pragma unroll
    for (int ks = 0; ks < 2; ks++){
      const int kvb = ks * 64 + rq * 16;
      bf16x8 af = *(const bf16x8*)(pbase + cl * 128 + (kvb ^ ((cl & 7) << 4)));
      #pragma unroll
      for (int n = 0; n < 8; n++){
        int r = n * 16 + cl;
        bf16x8 bfr = *(const bf16x8*)((const char*)Vs + r * 128 + (kvb ^ ((r & 7) << 4)));
        acco[n] = __builtin_amdgcn_mfma_f32_16x16x32_bf16(af, bfr, acco[n], 0, 0, 0);
      }
    }
    __syncthreads();
  }

  #pragma unroll
  for (int rr = 0; rr < 4; rr++){
    float inv = 1.0f / lst[rr];
    size_t grow = (size_t)(b * LL + qi * 64 + wv * 16 + rq * 4 + rr);
    #pragma unroll
    for (int n = 0; n < 8; n++)
      aout[grow * HIDD + h * HDD + n * 16 + cl] = f2bf(acco[n][rr] * inv);
  }
}

// ---------------- launcher ----------------

extern "C" void kernel_launch(void* const* d_in, const int* in_sizes, int n_in,
                              void* d_out, int out_size, void* d_ws, size_t ws_size,
                              hipStream_t stream)
{
  const float* x  = (const float*)d_in[0];
  // d_in[1] = mask (causal; applied analytically)
  const float* Wq = (const float*)d_in[2];
  const float* Wk = (const float*)d_in[3];
  const float* Wv = (const float*)d_in[4];
  const float* Wo = (const float*)d_in[5];
  float* out = (float*)d_out;

  if (ws_size < 134217728ull) return;  // need 128 MB of scratch

  char* ws = (char*)d_ws;
  u16* xb   = (u16*)(ws);                  // 4096x2048 bf16  (16 MB)
  u16* Wt   = (u16*)(ws + 16777216ull);    // 6144x2048 bf16  (24 MB) = [Wq|Wk|Wv]^T
  u16* Wot  = (u16*)(ws + 41943040ull);    // 2048x2048 bf16  ( 8 MB)
  u16* qkv  = (u16*)(ws + 50331648ull);    // 4096x6144 bf16  (48 MB)
  u16* vt   = (u16*)(ws + 100663296ull);   // 32x128x2048 bf16(16 MB)
  u16* aout = (u16*)(ws + 117440512ull);   // 4096x2048 bf16  (16 MB)

  cvt_f32_bf16_k<<<2097152 / 256, 256, 0, stream>>>(x, xb, 2097152);
  dim3 tb(32, 8);
  transpose_cvt_k<<<dim3(64, 64), tb, 0, stream>>>(Wq, Wt,                 2048, 2048);
  transpose_cvt_k<<<dim3(64, 64), tb, 0, stream>>>(Wk, Wt + 2048 * 2048,   2048, 2048);
  transpose_cvt_k<<<dim3(64, 64), tb, 0, stream>>>(Wv, Wt + 2 * 2048 * 2048, 2048, 2048);
  transpose_cvt_k<<<dim3(64, 64), tb, 0, stream>>>(Wo, Wot,                2048, 2048);

  gemm_bt_k<1><<<dim3(6144 / 128, 4096 / 128), 256, 0, stream>>>(xb, Wt, qkv, 4096, 6144, 2048);
  rope_k<<<4194304 / 256, 256, 0, stream>>>(qkv);
  build_vt_k<<<dim3(4, 64, 32), tb, 0, stream>>>(qkv, vt);
  attn_k<<<dim3(32, 32), 256, 0, stream>>>(qkv, vt, aout);
  gemm_bt_k<0><<<dim3(2048 / 128, 4096 / 128), 256, 0, stream>>>(aout, Wot, out, 4096, 2048, 2048);
}

// Round 2
// 330.830 us; speedup vs baseline: 1.1761x; 1.1761x over previous
//
#include <hip/hip_runtime.h>
#include <math.h>

#define BB   2
#define LL   2048
#define HIDD 2048
#define NHH  16
#define HDD  128
#define QKVN 6144   // 3*HIDD

typedef unsigned short u16;
typedef float  f32x4 __attribute__((ext_vector_type(4)));
typedef __bf16 bf16x8 __attribute__((ext_vector_type(8)));

static __device__ __forceinline__ u16 f2bf(float x){
  unsigned u = __float_as_uint(x);
  return (u16)((u + 0x7fffu + ((u >> 16) & 1u)) >> 16);
}
static __device__ __forceinline__ float bf2f(u16 b){
  return __uint_as_float(((unsigned)b) << 16);
}
static __device__ __forceinline__ void gl_lds16(const void* g, void* l){
  __builtin_amdgcn_global_load_lds(
      (__attribute__((address_space(1))) void*)(void*)g,
      (__attribute__((address_space(3))) void*)l,
      16, 0, 0);
}

// ---------------- prep kernels ----------------

__global__ void cvt_f32_bf16_k(const float* __restrict__ src, u16* __restrict__ dst, int n4){
  int i = blockIdx.x * blockDim.x + threadIdx.x;
  if (i >= n4) return;
  float4 v = ((const float4*)src)[i];
  ushort4 o;
  o.x = f2bf(v.x); o.y = f2bf(v.y); o.z = f2bf(v.z); o.w = f2bf(v.w);
  ((ushort4*)dst)[i] = o;
}

// src: R x C f32 (row-major) -> dst: C x R bf16
__global__ void transpose_cvt_k(const float* __restrict__ src, u16* __restrict__ dst, int R, int C){
  __shared__ float t[32][33];
  int c0 = blockIdx.x * 32, r0 = blockIdx.y * 32;
  int tx = threadIdx.x, ty = threadIdx.y;
  #pragma unroll
  for (int i = 0; i < 32; i += 8) t[ty + i][tx] = src[(size_t)(r0 + ty + i) * C + c0 + tx];
  __syncthreads();
  #pragma unroll
  for (int i = 0; i < 32; i += 8) dst[(size_t)(c0 + ty + i) * R + r0 + tx] = f2bf(t[tx][ty + i]);
}

// in-place RoPE on q,k sections of qkv (bf16). idx over B*L*NH*64
__global__ void rope_k(u16* __restrict__ qkv){
  int idx = blockIdx.x * blockDim.x + threadIdx.x;
  int d   = idx & 63;
  int h   = (idx >> 6) & 15;
  int row = idx >> 10;           // b*L + l
  int l   = row & (LL - 1);
  float fr = __expf(-(float)d * 0.17988946f);   // ln(1e5)/64
  float th = (float)l * 0.25f * fr;             // pos/ROPE_SCALE * freq
  float s, c;
  sincosf(th, &s, &c);
  size_t base = (size_t)row * QKVN + h * HDD + d;
  #pragma unroll
  for (int part = 0; part < 2; part++){         // q then k
    float x1 = bf2f(qkv[base]), x2 = bf2f(qkv[base + 64]);
    qkv[base]      = f2bf(x1 * c - x2 * s);
    qkv[base + 64] = f2bf(x1 * s + x2 * c);
    base += HIDD;
  }
}

// v section of qkv -> vt[(b,h), d, l]
__global__ void build_vt_k(const u16* __restrict__ qkv, u16* __restrict__ vt){
  __shared__ u16 t[32][33];
  int bh = blockIdx.z;
  int b = bh >> 4, h = bh & 15;
  const u16* src = qkv + (size_t)b * LL * QKVN + 2 * HIDD + h * HDD; // [l][d] stride QKVN
  u16* dst = vt + (size_t)bh * HDD * LL;                              // [d][l] stride LL
  int d0 = blockIdx.x * 32, l0 = blockIdx.y * 32;
  int tx = threadIdx.x, ty = threadIdx.y;
  #pragma unroll
  for (int i = 0; i < 32; i += 8) t[ty + i][tx] = src[(size_t)(l0 + ty + i) * QKVN + d0 + tx];
  __syncthreads();
  #pragma unroll
  for (int i = 0; i < 32; i += 8) dst[(size_t)(d0 + ty + i) * LL + l0 + tx] = t[tx][ty + i];
}

// ---------------- GEMM: C[M,N] = A[M,K] * Bt[N,K]^T  (bf16 in, f32 acc) ----------------

template<int OUT_BF16>
__global__ __launch_bounds__(256) void gemm_bt_k(
    const u16* __restrict__ A, const u16* __restrict__ Bt,
    void* __restrict__ Cout, int M, int N, int K)
{
  __shared__ __align__(16) u16 As[128 * 64];
  __shared__ __align__(16) u16 Bs[128 * 64];
  const int tid = threadIdx.x, lane = tid & 63, wv = tid >> 6;
  const int wr = wv >> 1, wc = wv & 1;
  const int m0 = blockIdx.y * 128, n0 = blockIdx.x * 128;
  const int rq = lane >> 4, cl = lane & 15;

  const f32x4 Z = {0.f, 0.f, 0.f, 0.f};
  f32x4 acc[4][4];
  #pragma unroll
  for (int m = 0; m < 4; m++)
    #pragma unroll
    for (int n = 0; n < 4; n++) acc[m][n] = Z;

  for (int kt = 0; kt < K; kt += 64){
    #pragma unroll
    for (int i = 0; i < 4; i++){
      int fb = (i * 4 + wv) * 64;          // wave-uniform 16B-chunk base
      int p  = (fb + lane) * 16;           // this lane's physical LDS byte
      int r  = p >> 7;                     // tile row (128B rows)
      int cbs = (p & 127) ^ ((r & 7) << 4);
      gl_lds16(A  + (size_t)(m0 + r) * K + kt + (cbs >> 1), &As[fb * 8]);
      gl_lds16(Bt + (size_t)(n0 + r) * K + kt + (cbs >> 1), &Bs[fb * 8]);
    }
    __syncthreads();
    #pragma unroll
    for (int ks = 0; ks < 2; ks++){
      const int kb = ks * 64 + rq * 16;    // k byte offset in row
      bf16x8 a[4], b[4];
      #pragma unroll
      for (int m = 0; m < 4; m++){
        int r = wr * 64 + m * 16 + cl;
        a[m] = *(const bf16x8*)((const char*)As + r * 128 + (kb ^ ((r & 7) << 4)));
      }
      #pragma unroll
      for (int n = 0; n < 4; n++){
        int r = wc * 64 + n * 16 + cl;
        b[n] = *(const bf16x8*)((const char*)Bs + r * 128 + (kb ^ ((r & 7) << 4)));
      }
      #pragma unroll
      for (int m = 0; m < 4; m++)
        #pragma unroll
        for (int n = 0; n < 4; n++)
          acc[m][n] = __builtin_amdgcn_mfma_f32_16x16x32_bf16(a[m], b[n], acc[m][n], 0, 0, 0);
    }
    __syncthreads();
  }

  #pragma unroll
  for (int m = 0; m < 4; m++){
    int gr0 = m0 + wr * 64 + m * 16 + rq * 4;
    #pragma unroll
    for (int n = 0; n < 4; n++){
      int gc = n0 + wc * 64 + n * 16 + cl;
      #pragma unroll
      for (int rr = 0; rr < 4; rr++){
        if (OUT_BF16) ((u16*)Cout)[(size_t)(gr0 + rr) * N + gc] = f2bf(acc[m][n][rr]);
        else          ((float*)Cout)[(size_t)(gr0 + rr) * N + gc] = acc[m][n][rr];
      }
    }
  }
}

// ---------------- flash attention ----------------
// grid: (B*NH=32, 16 q-tiles); block 256 = 4 waves x 32 q-rows (QBLK=128, KVBLK=64)
// double-buffered K/V staging, defer-max online softmax, LPT tile order.

#define STAGE(jj, bsel) do {                                                              \
  const int kv0_ = (jj) * 64;                                                             \
  _Pragma("unroll")                                                                       \
  for (int i_ = 0; i_ < 4; i_++){                                                         \
    int fb_ = (i_ * 4 + wv) * 64;                                                         \
    int p_  = (fb_ + lane) * 16;                                                          \
    { int r_ = p_ >> 8; int cb_ = (p_ & 255) ^ ((r_ & 7) << 4);                           \
      gl_lds16(qkv + (size_t)(b * LL + kv0_ + r_) * QKVN + HIDD + h * HDD + (cb_ >> 1),   \
               &Ks[bsel][fb_ * 8]); }                                                     \
    { int r_ = p_ >> 7; int cb_ = (p_ & 127) ^ ((r_ & 7) << 4);                           \
      gl_lds16(vt + (size_t)(bh * HDD + r_) * LL + kv0_ + (cb_ >> 1),                     \
               &Vs[bsel][fb_ * 8]); }                                                     \
  }                                                                                       \
} while(0)

__global__ __launch_bounds__(256, 2) void attn_k(
    const u16* __restrict__ qkv, const u16* __restrict__ vt,
    u16* __restrict__ aout)
{
  __shared__ __align__(16) u16 Ks[2][64 * 128];
  __shared__ __align__(16) u16 Vs[2][128 * 64];
  __shared__ __align__(16) u16 Ps[4][32 * 64];
  const int tid = threadIdx.x, lane = tid & 63, wv = tid >> 6;
  const int bh = blockIdx.x;
  const int qt = 15 - (int)blockIdx.y;          // long blocks dispatch first
  const int b = bh >> 4, h = bh & 15;
  const int rq = lane >> 4, cl = lane & 15;
  const float scale = 0.08838834764831845f;     // 1/sqrt(128)
  const int nj = 2 * qt + 2;

  // Q fragments: rows qt*128 + wv*32 + rt*16 + cl
  bf16x8 qf[2][4];
  #pragma unroll
  for (int rt = 0; rt < 2; rt++){
    const u16* qb = qkv + (size_t)(b * LL + qt * 128 + wv * 32 + rt * 16 + cl) * QKVN + h * HDD + rq * 8;
    #pragma unroll
    for (int ks = 0; ks < 4; ks++) qf[rt][ks] = *(const bf16x8*)(qb + ks * 32);
  }

  const f32x4 Z = {0.f, 0.f, 0.f, 0.f};
  f32x4 acco[2][8];
  float mst[2][4], lst[2][4];
  #pragma unroll
  for (int rt = 0; rt < 2; rt++){
    #pragma unroll
    for (int n = 0; n < 8; n++) acco[rt][n] = Z;
    #pragma unroll
    for (int rr = 0; rr < 4; rr++){ mst[rt][rr] = -INFINITY; lst[rt][rr] = 0.f; }
  }

  char* pbase = (char*)&Ps[wv][0];
  const int wrow_hi = qt * 128 + wv * 32 + 31;  // highest q row this wave owns

  STAGE(0, 0);
  __syncthreads();
  int cur = 0;

  for (int j = 0; j < nj; j++){
    if (j + 1 < nj) STAGE(j + 1, cur ^ 1);      // issue-early prefetch

    if (j * 64 <= wrow_hi){                     // wave has unmasked work in this tile
      const u16* KsC = Ks[cur];
      const u16* VsC = Vs[cur];

      // S = Q K^T : 32 q-rows x 64 kv per wave
      f32x4 s[2][4];
      #pragma unroll
      for (int rt = 0; rt < 2; rt++)
        #pragma unroll
        for (int ct = 0; ct < 4; ct++) s[rt][ct] = Z;
      #pragma unroll
      for (int ks = 0; ks < 4; ks++){
        const int kb = ks * 64 + rq * 16;
        #pragma unroll
        for (int ct = 0; ct < 4; ct++){
          int r = ct * 16 + cl;
          bf16x8 bfr = *(const bf16x8*)((const char*)KsC + r * 256 + (kb ^ ((r & 7) << 4)));
          #pragma unroll
          for (int rt = 0; rt < 2; rt++)
            s[rt][ct] = __builtin_amdgcn_mfma_f32_16x16x32_bf16(qf[rt][ks], bfr, s[rt][ct], 0, 0, 0);
        }
      }

      const bool msk = (j >= 2 * qt);           // only diagonal tiles need masking

      #pragma unroll
      for (int rt = 0; rt < 2; rt++){
        float p4[4][4], mx[4];
        #pragma unroll
        for (int rr = 0; rr < 4; rr++) mx[rr] = -1e30f;
        const int qg = qt * 128 + wv * 32 + rt * 16 + rq * 4;
        #pragma unroll
        for (int ct = 0; ct < 4; ct++){
          int col = j * 64 + ct * 16 + cl;
          #pragma unroll
          for (int rr = 0; rr < 4; rr++){
            float v = s[rt][ct][rr] * scale;
            if (msk && col > qg + rr) v = -1e30f;
            p4[ct][rr] = v;
            mx[rr] = fmaxf(mx[rr], v);
          }
        }
        #pragma unroll
        for (int off = 1; off < 16; off <<= 1)
          #pragma unroll
          for (int rr = 0; rr < 4; rr++)
            mx[rr] = fmaxf(mx[rr], __shfl_xor(mx[rr], off, 64));

        // defer-max: only rescale when the tile max grew by more than THR=8
        float need = 0.f;
        #pragma unroll
        for (int rr = 0; rr < 4; rr++) need = fmaxf(need, mx[rr] - mst[rt][rr]);
        if (!__all(need <= 8.f)){
          #pragma unroll
          for (int rr = 0; rr < 4; rr++){
            float mn  = fmaxf(mst[rt][rr], mx[rr]);
            float fsc = __expf(mst[rt][rr] - mn);
            mst[rt][rr] = mn;
            lst[rt][rr] *= fsc;
            #pragma unroll
            for (int n = 0; n < 8; n++) acco[rt][n][rr] *= fsc;
          }
        }

        float rs[4];
        #pragma unroll
        for (int rr = 0; rr < 4; rr++) rs[rr] = 0.f;
        #pragma unroll
        for (int ct = 0; ct < 4; ct++)
          #pragma unroll
          for (int rr = 0; rr < 4; rr++){
            float e = __expf(p4[ct][rr] - mst[rt][rr]);
            rs[rr] += e;
            int wr = rt * 16 + rq * 4 + rr;
            *(u16*)(pbase + wr * 128 + (((ct * 16 + cl) * 2) ^ ((wr & 7) << 4))) = f2bf(e);
          }
        #pragma unroll
        for (int off = 1; off < 16; off <<= 1)
          #pragma unroll
          for (int rr = 0; rr < 4; rr++)
            rs[rr] += __shfl_xor(rs[rr], off, 64);
        #pragma unroll
        for (int rr = 0; rr < 4; rr++) lst[rt][rr] += rs[rr];
      }

      // O += P V
      #pragma unroll
      for (int ks = 0; ks < 2; ks++){
        const int kvb = ks * 64 + rq * 16;
        bf16x8 pa[2];
        #pragma unroll
        for (int rt = 0; rt < 2; rt++){
          int wr = rt * 16 + cl;
          pa[rt] = *(const bf16x8*)(pbase + wr * 128 + (kvb ^ ((wr & 7) << 4)));
        }
        #pragma unroll
        for (int n = 0; n < 8; n++){
          int r = n * 16 + cl;
          bf16x8 bfr = *(const bf16x8*)((const char*)VsC + r * 128 + (kvb ^ ((r & 7) << 4)));
          #pragma unroll
          for (int rt = 0; rt < 2; rt++)
            acco[rt][n] = __builtin_amdgcn_mfma_f32_16x16x32_bf16(pa[rt], bfr, acco[rt][n], 0, 0, 0);
        }
      }
    }

    __syncthreads();
    cur ^= 1;
  }

  #pragma unroll
  for (int rt = 0; rt < 2; rt++)
    #pragma unroll
    for (int rr = 0; rr < 4; rr++){
      float inv = 1.0f / lst[rt][rr];
      size_t grow = (size_t)(b * LL + qt * 128 + wv * 32 + rt * 16 + rq * 4 + rr);
      #pragma unroll
      for (int n = 0; n < 8; n++)
        aout[grow * HIDD + h * HDD + n * 16 + cl] = f2bf(acco[rt][n][rr] * inv);
    }
}

// ---------------- launcher ----------------

extern "C" void kernel_launch(void* const* d_in, const int* in_sizes, int n_in,
                              void* d_out, int out_size, void* d_ws, size_t ws_size,
                              hipStream_t stream)
{
  const float* x  = (const float*)d_in[0];
  // d_in[1] = mask (causal; applied analytically)
  const float* Wq = (const float*)d_in[2];
  const float* Wk = (const float*)d_in[3];
  const float* Wv = (const float*)d_in[4];
  const float* Wo = (const float*)d_in[5];
  float* out = (float*)d_out;

  if (ws_size < 134217728ull) return;  // need 128 MB of scratch

  char* ws = (char*)d_ws;
  u16* xb   = (u16*)(ws);                  // 4096x2048 bf16  (16 MB)
  u16* Wt   = (u16*)(ws + 16777216ull);    // 6144x2048 bf16  (24 MB) = [Wq|Wk|Wv]^T
  u16* Wot  = (u16*)(ws + 41943040ull);    // 2048x2048 bf16  ( 8 MB)
  u16* qkv  = (u16*)(ws + 50331648ull);    // 4096x6144 bf16  (48 MB)
  u16* vt   = (u16*)(ws + 100663296ull);   // 32x128x2048 bf16(16 MB)
  u16* aout = (u16*)(ws + 117440512ull);   // 4096x2048 bf16  (16 MB)

  cvt_f32_bf16_k<<<2097152 / 256, 256, 0, stream>>>(x, xb, 2097152);
  dim3 tb(32, 8);
  transpose_cvt_k<<<dim3(64, 64), tb, 0, stream>>>(Wq, Wt,                   2048, 2048);
  transpose_cvt_k<<<dim3(64, 64), tb, 0, stream>>>(Wk, Wt + 2048 * 2048,     2048, 2048);
  transpose_cvt_k<<<dim3(64, 64), tb, 0, stream>>>(Wv, Wt + 2 * 2048 * 2048, 2048, 2048);
  transpose_cvt_k<<<dim3(64, 64), tb, 0, stream>>>(Wo, Wot,                  2048, 2048);

  gemm_bt_k<1><<<dim3(6144 / 128, 4096 / 128), 256, 0, stream>>>(xb, Wt, qkv, 4096, 6144, 2048);
  rope_k<<<4194304 / 256, 256, 0, stream>>>(qkv);
  build_vt_k<<<dim3(4, 64, 32), tb, 0, stream>>>(qkv, vt);
  attn_k<<<dim3(32, 16), 256, 0, stream>>>(qkv, vt, aout);
  gemm_bt_k<0><<<dim3(2048 / 128, 4096 / 128), 256, 0, stream>>>(aout, Wot, out, 4096, 2048, 2048);
}